// Round 1
// baseline (4487.282 us; speedup 1.0000x reference)
//
#include <hip/hip_runtime.h>
#include <hip/hip_bf16.h>

// Problem constants (from reference)
#define BATCHN 256
#define SEQL   8
#define HIDN   1024      // HID == HSS
#define DIN    2048      // D_INNER
#define NH     32        // NHEADS
#define HDIM   64        // HEADDIM
#define DST    128       // DSTATE
#define CONVD  2304      // CONV_DIM = DIN + 2*DST
#define DPROJ  4384      // 2*DIN + 2*DST + NH
#define ROWS   2048      // BATCH*SEQ

// ---------------------------------------------------------------------------
// Tiled fp32 GEMM, C[M,N] = A[M,K] @ W[K,N] (+bias) (optional relu).
// BM=BN=64, BK=32, 256 threads, 4x4 micro-tile per thread.
// A-tile stored transposed in LDS with pad 68 (68 floats = 17*16B, keeps
// float4 reads aligned). Guards on M and N edges (N=4384, N=2 cases).
// ---------------------------------------------------------------------------
template<bool RELU>
__global__ __launch_bounds__(256)
void gemm_nn(const float* __restrict__ A, const float* __restrict__ W,
             const float* __restrict__ bias, float* __restrict__ C,
             int M, int N, int K)
{
    constexpr int BM = 64, BN = 64, BK = 32;
    __shared__ float As[BK][68];   // [k][m], padded
    __shared__ float Bs[BK][BN];   // [k][n]
    const int row0 = blockIdx.y * BM;
    const int col0 = blockIdx.x * BN;
    const int tid  = threadIdx.x;
    const int tx   = tid & 15;     // n-group
    const int ty   = tid >> 4;     // m-group
    float acc[4][4] = {};

    for (int k0 = 0; k0 < K; k0 += BK) {
#pragma unroll
        for (int i = 0; i < 8; ++i) {            // A tile: 64x32
            int idx = tid + i * 256;
            int r = idx >> 5, c = idx & 31;
            int gr = row0 + r;
            float v = (gr < M) ? A[(size_t)gr * K + (k0 + c)] : 0.f;
            As[c][r] = v;
        }
#pragma unroll
        for (int i = 0; i < 8; ++i) {            // W tile: 32x64
            int idx = tid + i * 256;
            int r = idx >> 6, c = idx & 63;
            int gc = col0 + c;
            Bs[r][c] = (gc < N) ? W[(size_t)(k0 + r) * N + gc] : 0.f;
        }
        __syncthreads();
#pragma unroll
        for (int k = 0; k < BK; ++k) {
            float4 a4 = *reinterpret_cast<const float4*>(&As[k][ty * 4]);
            float4 b4 = *reinterpret_cast<const float4*>(&Bs[k][tx * 4]);
            float av[4] = {a4.x, a4.y, a4.z, a4.w};
            float bv[4] = {b4.x, b4.y, b4.z, b4.w};
#pragma unroll
            for (int i = 0; i < 4; ++i)
#pragma unroll
                for (int j = 0; j < 4; ++j)
                    acc[i][j] = fmaf(av[i], bv[j], acc[i][j]);
        }
        __syncthreads();
    }

#pragma unroll
    for (int i = 0; i < 4; ++i) {
        int r = row0 + ty * 4 + i;
        if (r >= M) continue;
#pragma unroll
        for (int j = 0; j < 4; ++j) {
            int c = col0 + tx * 4 + j;
            if (c >= N) continue;
            float v = acc[i][j] + (bias ? bias[c] : 0.f);
            if (RELU) v = fmaxf(v, 0.f);
            C[(size_t)r * N + c] = v;
        }
    }
}

// ---------------------------------------------------------------------------
// Depthwise causal conv over L=8 (+bias, silu). One thread per (b, channel).
// Input: zx (ROWS x DPROJ), channels at cols [DIN, DIN+CONVD).
// Output: xbc (ROWS x CONVD), activated.
// ---------------------------------------------------------------------------
__global__ __launch_bounds__(256)
void conv_kernel(const float* __restrict__ zx, const float* __restrict__ cw,
                 const float* __restrict__ cb, float* __restrict__ xbc)
{
    int g = blockIdx.x * 256 + threadIdx.x;
    if (g >= BATCHN * CONVD) return;
    int c = g % CONVD;
    int b = g / CONVD;
    float x8[SEQL];
#pragma unroll
    for (int l = 0; l < SEQL; ++l)
        x8[l] = zx[(size_t)(b * SEQL + l) * DPROJ + DIN + c];
    float w0 = cw[c * 4 + 0], w1 = cw[c * 4 + 1];
    float w2 = cw[c * 4 + 2], w3 = cw[c * 4 + 3];
    float bb = cb[c];
#pragma unroll
    for (int l = 0; l < SEQL; ++l) {
        float s = bb;
        if (l >= 3) s = fmaf(w0, x8[l - 3], s);
        if (l >= 2) s = fmaf(w1, x8[l - 2], s);
        if (l >= 1) s = fmaf(w2, x8[l - 1], s);
        s = fmaf(w3, x8[l], s);
        float a = s / (1.f + __expf(-s));        // silu
        xbc[(size_t)(b * SEQL + l) * CONVD + c] = a;
    }
}

// ---------------------------------------------------------------------------
// dt = softplus(dt_raw + dt_bias); dA = exp(-exp(A_log) * dt).
// One thread per (row, head). dt_raw at zx cols [DIN+CONVD, DPROJ).
// ---------------------------------------------------------------------------
__global__ __launch_bounds__(256)
void dt_kernel(const float* __restrict__ zx, const float* __restrict__ dt_bias,
               const float* __restrict__ A_log, float* __restrict__ dtb,
               float* __restrict__ dab)
{
    int i = blockIdx.x * 256 + threadIdx.x;      // row*NH + h
    if (i >= ROWS * NH) return;
    int row = i >> 5, h = i & 31;
    float v = zx[(size_t)row * DPROJ + (DIN + CONVD) + h] + dt_bias[h];
    float dt = (v > 20.f) ? v : log1pf(__expf(v));
    float dA = __expf(-__expf(A_log[h]) * dt);
    dtb[i] = dt;
    dab[i] = dA;
}

// ---------------------------------------------------------------------------
// Selective scan. One block per (b, h). 256 threads: t = sc*64 + p,
// sc in [0,4) covers a 32-wide slice of DSTATE, p in [0,64) is headdim.
// State st[32] in registers. B_t/C_t staged in LDS (wave-uniform broadcast
// reads). y reduction across the 4 sc-waves via LDS.
// y[row, h*64+p] = sum_s h_new[p][s]*C[s] + D[h]*x[p]
// ---------------------------------------------------------------------------
__global__ __launch_bounds__(256)
void scan_kernel(const float* __restrict__ xbc, const float* __restrict__ dtb,
                 const float* __restrict__ dab, const float* __restrict__ Dv,
                 float* __restrict__ y)
{
    const int b  = blockIdx.x >> 5;
    const int h  = blockIdx.x & 31;
    const int t  = threadIdx.x;
    const int sc = t >> 6;
    const int p  = t & 63;
    __shared__ float BC[256];      // [0,128): B_t, [128,256): C_t
    __shared__ float part[256];
    float st[32];
#pragma unroll
    for (int j = 0; j < 32; ++j) st[j] = 0.f;
    const float Dh = Dv[h];

    for (int l = 0; l < SEQL; ++l) {
        const int row = b * SEQL + l;
        BC[t] = xbc[(size_t)row * CONVD + DIN + t];   // B (128) then C (128)
        __syncthreads();
        const float dA = dab[row * NH + h];
        const float dt = dtb[row * NH + h];
        const float xp = xbc[(size_t)row * CONVD + h * HDIM + p];
        const float coef = dt * xp;
        float acc = 0.f;
#pragma unroll
        for (int j = 0; j < 32; ++j) {
            const int s = sc * 32 + j;
            st[j] = fmaf(dA, st[j], coef * BC[s]);
            acc = fmaf(st[j], BC[128 + s], acc);
        }
        part[t] = acc;
        __syncthreads();
        if (sc == 0) {
            float yv = part[p] + part[64 + p] + part[128 + p] + part[192 + p];
            y[(size_t)row * DIN + h * HDIM + p] = yv + Dh * xp;
        }
    }
}

// ---------------------------------------------------------------------------
// y = y * silu(z); rmsnorm over 2048; * norm_w. In-place on y.
// One block per row, 8 elements per thread.
// ---------------------------------------------------------------------------
__global__ __launch_bounds__(256)
void gate_rms(float* __restrict__ y, const float* __restrict__ zx,
              const float* __restrict__ nw)
{
    const int row = blockIdx.x;
    const int t = threadIdx.x;
    float g[8];
    float ss = 0.f;
#pragma unroll
    for (int i = 0; i < 8; ++i) {
        int d = t + i * 256;
        float yv = y[(size_t)row * DIN + d];
        float zv = zx[(size_t)row * DPROJ + d];
        float sil = zv / (1.f + __expf(-zv));
        float gv = yv * sil;
        g[i] = gv;
        ss = fmaf(gv, gv, ss);
    }
#pragma unroll
    for (int o = 32; o >= 1; o >>= 1) ss += __shfl_xor(ss, o, 64);
    __shared__ float red[4];
    if ((t & 63) == 0) red[t >> 6] = ss;
    __syncthreads();
    float tot = red[0] + red[1] + red[2] + red[3];
    float scale = rsqrtf(tot * (1.f / DIN) + 1e-5f);
#pragma unroll
    for (int i = 0; i < 8; ++i) {
        int d = t + i * 256;
        y[(size_t)row * DIN + d] = g[i] * scale * nw[d];
    }
}

// ---------------------------------------------------------------------------
static void mamba_layer(const float* act_in, const float* in_proj,
                        const float* conv_w, const float* conv_b,
                        const float* dt_bias, const float* A_log,
                        const float* Dv, const float* norm_w,
                        const float* out_proj,
                        float* zx, float* xbc, float* dtb, float* dab,
                        float* y, float* act_out, hipStream_t stream)
{
    // zxbcdt = act_in @ in_proj   (2048 x 4384, K=1024)
    gemm_nn<false><<<dim3((DPROJ + 63) / 64, ROWS / 64), 256, 0, stream>>>(
        act_in, in_proj, nullptr, zx, ROWS, DPROJ, HIDN);
    conv_kernel<<<(BATCHN * CONVD + 255) / 256, 256, 0, stream>>>(zx, conv_w, conv_b, xbc);
    dt_kernel<<<(ROWS * NH) / 256, 256, 0, stream>>>(zx, dt_bias, A_log, dtb, dab);
    scan_kernel<<<BATCHN * NH, 256, 0, stream>>>(xbc, dtb, dab, Dv, y);
    gate_rms<<<ROWS, 256, 0, stream>>>(y, zx, norm_w);
    // act_out = y @ out_proj   (2048 x 1024, K=2048)
    gemm_nn<false><<<dim3(HIDN / 64, ROWS / 64), 256, 0, stream>>>(
        y, out_proj, nullptr, act_out, ROWS, HIDN, DIN);
}

extern "C" void kernel_launch(void* const* d_in, const int* in_sizes, int n_in,
                              void* d_out, int out_size, void* d_ws, size_t ws_size,
                              hipStream_t stream)
{
    const float* x      = (const float*)d_in[0];
    const float* w_in1  = (const float*)d_in[1];
    const float* b_in1  = (const float*)d_in[2];
    const float* w_in2  = (const float*)d_in[3];
    const float* b_in2  = (const float*)d_in[4];
    const float* m_in_proj[2]  = {(const float*)d_in[5],  (const float*)d_in[13]};
    const float* m_conv_w[2]   = {(const float*)d_in[6],  (const float*)d_in[14]};
    const float* m_conv_b[2]   = {(const float*)d_in[7],  (const float*)d_in[15]};
    const float* m_dt_bias[2]  = {(const float*)d_in[8],  (const float*)d_in[16]};
    const float* m_A_log[2]    = {(const float*)d_in[9],  (const float*)d_in[17]};
    const float* m_D[2]        = {(const float*)d_in[10], (const float*)d_in[18]};
    const float* m_norm_w[2]   = {(const float*)d_in[11], (const float*)d_in[19]};
    const float* m_out_proj[2] = {(const float*)d_in[12], (const float*)d_in[20]};
    const float* w_out1 = (const float*)d_in[21];
    const float* b_out1 = (const float*)d_in[22];
    const float* w_out2 = (const float*)d_in[23];
    const float* b_out2 = (const float*)d_in[24];
    float* out = (float*)d_out;

    // Workspace layout (floats). Total = 20,381,696 floats = 81.5 MB.
    float* ws   = (float*)d_ws;
    float* h1y  = ws;               // max(256*8192 h1, 2048*2048 y) = 4,194,304
    float* act  = h1y + 4194304;    // 2048*1024 = 2,097,152 (also 256*8192 view)
    float* zx   = act + 2097152;    // 2048*4384 = 8,978,432
    float* xbc  = zx  + 8978432;    // 2048*2304 = 4,718,592
    float* dtb  = xbc + 4718592;    // 65,536
    float* dab  = dtb + 65536;      // 65,536
    float* f1   = dab + 65536;      // 256*1024 = 262,144

    // h1 = relu(x @ w_in1 + b_in1)           (256 x 8192, K=1024)
    gemm_nn<true ><<<dim3(8192 / 64, BATCHN / 64), 256, 0, stream>>>(
        x, w_in1, b_in1, h1y, BATCHN, 8192, HIDN);
    // act = h1 @ w_in2 + b_in2               (256 x 8192, K=8192)
    gemm_nn<false><<<dim3(8192 / 64, BATCHN / 64), 256, 0, stream>>>(
        h1y, w_in2, b_in2, act, BATCHN, 8192, 8192);

    // Two mamba layers; act is (2048 x 1024) view of (256 x 8192). In-place
    // act update is safe: act is only read by the in_proj GEMM.
    for (int m = 0; m < 2; ++m) {
        mamba_layer(act, m_in_proj[m], m_conv_w[m], m_conv_b[m], m_dt_bias[m],
                    m_A_log[m], m_D[m], m_norm_w[m], m_out_proj[m],
                    zx, xbc, dtb, dab, h1y /*y*/, act, stream);
    }

    // f1 = relu(act @ w_out1 + b_out1)       (256 x 1024, K=8192)
    gemm_nn<true ><<<dim3(1024 / 64, BATCHN / 64), 256, 0, stream>>>(
        act, w_out1, b_out1, f1, BATCHN, 1024, 8192);
    // out = f1 @ w_out2 + b_out2             (256 x 2, K=1024)
    gemm_nn<false><<<dim3(1, BATCHN / 64), 256, 0, stream>>>(
        f1, w_out2, b_out2, out, BATCHN, 2, 1024);
}

// Round 2
// 1024.387 us; speedup vs baseline: 4.3805x; 4.3805x over previous
//
#include <hip/hip_runtime.h>

// Problem constants
#define BATCHN 256
#define SEQL   8
#define HIDN   1024
#define DIN    2048
#define NH     32
#define HDIM   64
#define DST    128
#define CONVD  2304      // DIN + 2*DST
#define DPROJ  4384      // 2*DIN + 2*DST + NH
#define DPROJP 4480      // DPROJ padded to x128 for GEMM-N
#define ROWS   2048      // BATCH*SEQ

typedef float f32x4 __attribute__((ext_vector_type(4)));
typedef short bf16x8 __attribute__((ext_vector_type(8)));   // 8 bf16 in 4 VGPRs

__device__ __forceinline__ ushort f2bf(float f) {           // RNE fp32->bf16
    unsigned x = __float_as_uint(f);
    unsigned r = (x + 0x7fffu + ((x >> 16) & 1u)) >> 16;
    return (ushort)r;
}
__device__ __forceinline__ float bf2f(ushort u) {
    return __uint_as_float(((unsigned)u) << 16);
}

#define GL2LDS(g, l)                                                        \
    __builtin_amdgcn_global_load_lds(                                       \
        (const __attribute__((address_space(1))) void*)(g),                 \
        (__attribute__((address_space(3))) void*)(l), 16, 0, 0)

// ---------------------------------------------------------------------------
// Transpose-convert: W [K][N] fp32 (row-major) -> Wt [Npad][K] bf16.
// Rows n in [N, Npad) are zero-filled. 64x64 tiles, float4 loads, ushort4
// stores. grid = (Npad/64, K/64), block = 256.
// ---------------------------------------------------------------------------
__global__ __launch_bounds__(256)
void transpose_bf16(const float* __restrict__ W, ushort* __restrict__ Wt,
                    int N, int K)
{
    __shared__ float tile[64][65];
    const int n0 = blockIdx.x * 64;
    const int k0 = blockIdx.y * 64;
    const int t  = threadIdx.x;
    const int ln = (t & 15) * 4;
    const int lk = t >> 4;
#pragma unroll
    for (int i = 0; i < 4; ++i) {
        const int k  = lk + i * 16;
        const int gn = n0 + ln;
        float4 v;
        if (gn + 3 < N) {
            v = *reinterpret_cast<const float4*>(&W[(size_t)(k0 + k) * N + gn]);
        } else {
            v.x = (gn + 0 < N) ? W[(size_t)(k0 + k) * N + gn + 0] : 0.f;
            v.y = (gn + 1 < N) ? W[(size_t)(k0 + k) * N + gn + 1] : 0.f;
            v.z = (gn + 2 < N) ? W[(size_t)(k0 + k) * N + gn + 2] : 0.f;
            v.w = (gn + 3 < N) ? W[(size_t)(k0 + k) * N + gn + 3] : 0.f;
        }
        tile[k][ln + 0] = v.x; tile[k][ln + 1] = v.y;
        tile[k][ln + 2] = v.z; tile[k][ln + 3] = v.w;
    }
    __syncthreads();
    const int wk = (t & 15) * 4;
    const int wn = t >> 4;
#pragma unroll
    for (int i = 0; i < 4; ++i) {
        const int n = wn + i * 16;
        ushort4 o;
        o.x = f2bf(tile[wk + 0][n]);
        o.y = f2bf(tile[wk + 1][n]);
        o.z = f2bf(tile[wk + 2][n]);
        o.w = f2bf(tile[wk + 3][n]);
        *reinterpret_cast<ushort4*>(&Wt[(size_t)(n0 + n) * K + k0 + wk]) = o;
    }
}

// ---------------------------------------------------------------------------
// bf16 MFMA GEMM: C[M,N] = A[M,K] @ Bt[N,K]^T.
// A bf16 row-major (lda), Bt bf16 row-major (ldb). 128x128 tile, BK=32,
// 256 threads = 4 waves in 2x2, each wave 64x64 via 4x4 mfma_16x16x32_bf16.
// global_load_lds width-16 staging, m97 2-barrier structure.
// OM: 0 = fp32 store, 1 = bf16 store, 2 = fp32 atomicAdd (split-K).
// Split-K via blockIdx.z * kchunk. M,N multiples of 128; K chunks x32.
// ---------------------------------------------------------------------------
template<int OM, bool BIASF, bool RELUF>
__global__ __launch_bounds__(256)
void gemm_bf16(const ushort* __restrict__ A, int lda,
               const ushort* __restrict__ Bt, int ldb,
               const float* __restrict__ bias,
               void* __restrict__ Cv, int ldc,
               int kLen, int kchunk)
{
    __shared__ __align__(16) ushort As[128 * 32];
    __shared__ __align__(16) ushort Bs[128 * 32];
    const int t    = threadIdx.x;
    const int row0 = blockIdx.y * 128;
    const int col0 = blockIdx.x * 128;
    const int kOff = blockIdx.z * kchunk;
    const int kEnd = min(kLen, kOff + kchunk);
    const int lane = t & 63;
    const int wv   = t >> 6;
    const int wr   = wv >> 1, wc = wv & 1;
    const int frow = lane & 15;
    const int fko  = (lane >> 4) * 8;

    f32x4 acc[4][4];
#pragma unroll
    for (int m = 0; m < 4; ++m)
#pragma unroll
        for (int n = 0; n < 4; ++n) acc[m][n] = f32x4{0.f, 0.f, 0.f, 0.f};

    const int sRow = t >> 2;
    const int sCol = (t & 3) * 8;
    const ushort* aBase = A  + (size_t)(row0 + sRow) * lda + sCol;
    const ushort* bBase = Bt + (size_t)(col0 + sRow) * ldb + sCol;
    ushort* aL = As + t * 8;
    ushort* bL = Bs + t * 8;

    for (int kg = kOff; kg < kEnd; kg += 32) {
        GL2LDS(aBase + kg, aL);
        GL2LDS(aBase + (size_t)64 * lda + kg, aL + 2048);
        GL2LDS(bBase + kg, bL);
        GL2LDS(bBase + (size_t)64 * ldb + kg, bL + 2048);
        __syncthreads();
        bf16x8 af[4], bfr[4];
#pragma unroll
        for (int m = 0; m < 4; ++m)
            af[m] = *reinterpret_cast<const bf16x8*>(&As[(wr * 64 + m * 16 + frow) * 32 + fko]);
#pragma unroll
        for (int n = 0; n < 4; ++n)
            bfr[n] = *reinterpret_cast<const bf16x8*>(&Bs[(wc * 64 + n * 16 + frow) * 32 + fko]);
#pragma unroll
        for (int m = 0; m < 4; ++m)
#pragma unroll
            for (int n = 0; n < 4; ++n)
                acc[m][n] = __builtin_amdgcn_mfma_f32_16x16x32_bf16(af[m], bfr[n], acc[m][n], 0, 0, 0);
        __syncthreads();
    }

    float*  Cf = (float*)Cv;
    ushort* Cb = (ushort*)Cv;
    const int colBase = col0 + wc * 64;
    const int rowBase = row0 + wr * 64 + (lane >> 4) * 4;
#pragma unroll
    for (int n = 0; n < 4; ++n) {
        const int col = colBase + n * 16 + frow;
        const float bv = BIASF ? bias[col] : 0.f;
#pragma unroll
        for (int m = 0; m < 4; ++m) {
#pragma unroll
            for (int r = 0; r < 4; ++r) {
                const int row = rowBase + m * 16 + r;
                float v = acc[m][n][r] + bv;
                if (RELUF) v = fmaxf(v, 0.f);
                if (OM == 0)      Cf[(size_t)row * ldc + col] = v;
                else if (OM == 1) Cb[(size_t)row * ldc + col] = f2bf(v);
                else              atomicAdd(&Cf[(size_t)row * ldc + col], v);
            }
        }
    }
}

// ---------------------------------------------------------------------------
// fp32 -> bf16 elementwise (x input). 4 elems/thread.
// ---------------------------------------------------------------------------
__global__ __launch_bounds__(256)
void convert_bf16(const float* __restrict__ in, ushort* __restrict__ out)
{
    int i = (blockIdx.x * 256 + threadIdx.x) * 4;
    float4 v = *reinterpret_cast<const float4*>(&in[i]);
    ushort4 o = {f2bf(v.x), f2bf(v.y), f2bf(v.z), f2bf(v.w)};
    *reinterpret_cast<ushort4*>(&out[i]) = o;
}

// ---------------------------------------------------------------------------
// Split-K epilogue: out_bf16 = [relu](acc + bias[col]).  N power of 2.
// ---------------------------------------------------------------------------
template<bool RELUF>
__global__ __launch_bounds__(256)
void post_bias(const float* __restrict__ acc, const float* __restrict__ bias,
               ushort* __restrict__ out, int nmask)
{
    int i = (blockIdx.x * 256 + threadIdx.x) * 4;
    float4 v = *reinterpret_cast<const float4*>(&acc[i]);
    int col = i & nmask;
    float4 b = *reinterpret_cast<const float4*>(&bias[col]);
    float r0 = v.x + b.x, r1 = v.y + b.y, r2 = v.z + b.z, r3 = v.w + b.w;
    if (RELUF) {
        r0 = fmaxf(r0, 0.f); r1 = fmaxf(r1, 0.f);
        r2 = fmaxf(r2, 0.f); r3 = fmaxf(r3, 0.f);
    }
    ushort4 o = {f2bf(r0), f2bf(r1), f2bf(r2), f2bf(r3)};
    *reinterpret_cast<ushort4*>(&out[i]) = o;
}

// ---------------------------------------------------------------------------
// Depthwise causal conv over L=8 (+bias, silu). One thread per (b, channel).
// zx stride DPROJP. Output xbc (ROWS x CONVD), activated.
// ---------------------------------------------------------------------------
__global__ __launch_bounds__(256)
void conv_kernel(const float* __restrict__ zx, const float* __restrict__ cw,
                 const float* __restrict__ cb, float* __restrict__ xbc)
{
    int g = blockIdx.x * 256 + threadIdx.x;
    if (g >= BATCHN * CONVD) return;
    int c = g % CONVD;
    int b = g / CONVD;
    float x8[SEQL];
#pragma unroll
    for (int l = 0; l < SEQL; ++l)
        x8[l] = zx[(size_t)(b * SEQL + l) * DPROJP + DIN + c];
    float w0 = cw[c * 4 + 0], w1 = cw[c * 4 + 1];
    float w2 = cw[c * 4 + 2], w3 = cw[c * 4 + 3];
    float bb = cb[c];
#pragma unroll
    for (int l = 0; l < SEQL; ++l) {
        float s = bb;
        if (l >= 3) s = fmaf(w0, x8[l - 3], s);
        if (l >= 2) s = fmaf(w1, x8[l - 2], s);
        if (l >= 1) s = fmaf(w2, x8[l - 1], s);
        s = fmaf(w3, x8[l], s);
        float a = s / (1.f + __expf(-s));
        xbc[(size_t)(b * SEQL + l) * CONVD + c] = a;
    }
}

__global__ __launch_bounds__(256)
void dt_kernel(const float* __restrict__ zx, const float* __restrict__ dt_bias,
               const float* __restrict__ A_log, float* __restrict__ dtb,
               float* __restrict__ dab)
{
    int i = blockIdx.x * 256 + threadIdx.x;      // row*NH + h
    if (i >= ROWS * NH) return;
    int row = i >> 5, h = i & 31;
    float v = zx[(size_t)row * DPROJP + (DIN + CONVD) + h] + dt_bias[h];
    float dt = (v > 20.f) ? v : log1pf(__expf(v));
    float dA = __expf(-__expf(A_log[h]) * dt);
    dtb[i] = dt;
    dab[i] = dA;
}

// ---------------------------------------------------------------------------
// Selective scan. One block per (b, h). See round-1 notes; unchanged.
// ---------------------------------------------------------------------------
__global__ __launch_bounds__(256)
void scan_kernel(const float* __restrict__ xbc, const float* __restrict__ dtb,
                 const float* __restrict__ dab, const float* __restrict__ Dv,
                 float* __restrict__ y)
{
    const int b  = blockIdx.x >> 5;
    const int h  = blockIdx.x & 31;
    const int t  = threadIdx.x;
    const int sc = t >> 6;
    const int p  = t & 63;
    __shared__ float BC[256];
    __shared__ float part[256];
    float st[32];
#pragma unroll
    for (int j = 0; j < 32; ++j) st[j] = 0.f;
    const float Dh = Dv[h];

    for (int l = 0; l < SEQL; ++l) {
        const int row = b * SEQL + l;
        BC[t] = xbc[(size_t)row * CONVD + DIN + t];
        __syncthreads();
        const float dA = dab[row * NH + h];
        const float dt = dtb[row * NH + h];
        const float xp = xbc[(size_t)row * CONVD + h * HDIM + p];
        const float coef = dt * xp;
        float acc = 0.f;
#pragma unroll
        for (int j = 0; j < 32; ++j) {
            const int s = sc * 32 + j;
            st[j] = fmaf(dA, st[j], coef * BC[s]);
            acc = fmaf(st[j], BC[128 + s], acc);
        }
        part[t] = acc;
        __syncthreads();
        if (sc == 0) {
            float yv = part[p] + part[64 + p] + part[128 + p] + part[192 + p];
            y[(size_t)row * DIN + h * HDIM + p] = yv + Dh * xp;
        }
    }
}

// ---------------------------------------------------------------------------
// y = y * silu(z); rmsnorm over 2048; * norm_w; emit bf16.
// ---------------------------------------------------------------------------
__global__ __launch_bounds__(256)
void gate_rms(const float* __restrict__ y, const float* __restrict__ zx,
              const float* __restrict__ nw, ushort* __restrict__ yb)
{
    const int row = blockIdx.x;
    const int t = threadIdx.x;
    float g[8];
    float ss = 0.f;
#pragma unroll
    for (int i = 0; i < 8; ++i) {
        int d = t + i * 256;
        float yv = y[(size_t)row * DIN + d];
        float zv = zx[(size_t)row * DPROJP + d];
        float sil = zv / (1.f + __expf(-zv));
        float gv = yv * sil;
        g[i] = gv;
        ss = fmaf(gv, gv, ss);
    }
#pragma unroll
    for (int o = 32; o >= 1; o >>= 1) ss += __shfl_xor(ss, o, 64);
    __shared__ float red[4];
    if ((t & 63) == 0) red[t >> 6] = ss;
    __syncthreads();
    float tot = red[0] + red[1] + red[2] + red[3];
    float scale = rsqrtf(tot * (1.f / DIN) + 1e-5f);
#pragma unroll
    for (int i = 0; i < 8; ++i) {
        int d = t + i * 256;
        yb[(size_t)row * DIN + d] = f2bf(g[i] * scale * nw[d]);
    }
}

// ---------------------------------------------------------------------------
// Final tiny GEMM: out[256,2] = f1b(bf16) @ w_out2(fp32) + b_out2.
// One wave per row, shuffle reduce. grid 64 x 256thr.
// ---------------------------------------------------------------------------
__global__ __launch_bounds__(256)
void final_out(const ushort* __restrict__ f1b, const float* __restrict__ w2,
               const float* __restrict__ b2, float* __restrict__ out)
{
    int row  = blockIdx.x * 4 + (threadIdx.x >> 6);
    int lane = threadIdx.x & 63;
    float a0 = 0.f, a1 = 0.f;
#pragma unroll
    for (int i = 0; i < 16; ++i) {
        int k = lane + i * 64;
        float f = bf2f(f1b[row * 1024 + k]);
        a0 = fmaf(f, w2[k * 2 + 0], a0);
        a1 = fmaf(f, w2[k * 2 + 1], a1);
    }
#pragma unroll
    for (int o = 32; o >= 1; o >>= 1) {
        a0 += __shfl_xor(a0, o, 64);
        a1 += __shfl_xor(a1, o, 64);
    }
    if (lane == 0) {
        out[row * 2 + 0] = a0 + b2[0];
        out[row * 2 + 1] = a1 + b2[1];
    }
}

// ---------------------------------------------------------------------------
extern "C" void kernel_launch(void* const* d_in, const int* in_sizes, int n_in,
                              void* d_out, int out_size, void* d_ws, size_t ws_size,
                              hipStream_t stream)
{
    const float* x      = (const float*)d_in[0];
    const float* w_in1  = (const float*)d_in[1];
    const float* b_in1  = (const float*)d_in[2];
    const float* w_in2  = (const float*)d_in[3];
    const float* b_in2  = (const float*)d_in[4];
    const float* m_in_proj[2]  = {(const float*)d_in[5],  (const float*)d_in[13]};
    const float* m_conv_w[2]   = {(const float*)d_in[6],  (const float*)d_in[14]};
    const float* m_conv_b[2]   = {(const float*)d_in[7],  (const float*)d_in[15]};
    const float* m_dt_bias[2]  = {(const float*)d_in[8],  (const float*)d_in[16]};
    const float* m_A_log[2]    = {(const float*)d_in[9],  (const float*)d_in[17]};
    const float* m_D[2]        = {(const float*)d_in[10], (const float*)d_in[18]};
    const float* m_norm_w[2]   = {(const float*)d_in[11], (const float*)d_in[19]};
    const float* m_out_proj[2] = {(const float*)d_in[12], (const float*)d_in[20]};
    const float* w_out1 = (const float*)d_in[21];
    const float* b_out1 = (const float*)d_in[22];
    const float* w_out2 = (const float*)d_in[23];
    const float* b_out2 = (const float*)d_in[24];
    float* out = (float*)d_out;

    // Workspace layout (bytes, 256-aligned). Total ~127 MiB.
    char* p = (char*)d_ws;
    ushort* wT   = (ushort*)p;                 p += (size_t)8192 * 2048 * 2;  // 33.55 MB (max weight slab)
    ushort* xb   = (ushort*)p;                 p += (size_t)256 * 1024 * 2;
    ushort* h1b  = (ushort*)p;                 p += (size_t)256 * 8192 * 2;
    ushort* actb = (ushort*)p;                 p += (size_t)2048 * 1024 * 2;
    float*  cacc = (float*)p;                  p += (size_t)256 * 8192 * 4;   // split-K accum
    float*  zx   = (float*)p;                  p += (size_t)ROWS * DPROJP * 4;
    float*  xbc  = (float*)p;                  p += (size_t)ROWS * CONVD * 4;
    float*  dtb  = (float*)p;                  p += (size_t)ROWS * NH * 4;
    float*  dab  = (float*)p;                  p += (size_t)ROWS * NH * 4;
    float*  yf   = (float*)p;                  p += (size_t)ROWS * DIN * 4;
    ushort* yb   = (ushort*)p;                 p += (size_t)ROWS * DIN * 2;
    ushort* f1b  = (ushort*)p;                 p += (size_t)256 * 1024 * 2;

    // x -> bf16
    convert_bf16<<<256, 256, 0, stream>>>(x, xb);

    // h1 = relu(x @ w_in1 + b1) -> bf16          [256 x 8192, K=1024]
    transpose_bf16<<<dim3(8192 / 64, 1024 / 64), 256, 0, stream>>>(w_in1, wT, 8192, 1024);
    gemm_bf16<1, true, true><<<dim3(64, 2, 1), 256, 0, stream>>>(
        xb, 1024, wT, 1024, b_in1, h1b, 8192, 1024, 1024);

    // act = h1 @ w_in2 + b2 -> bf16              [256 x 8192, K=8192], 4 K-strips
    hipMemsetAsync(cacc, 0, (size_t)256 * 8192 * 4, stream);
    for (int c = 0; c < 4; ++c) {
        transpose_bf16<<<dim3(8192 / 64, 2048 / 64), 256, 0, stream>>>(
            w_in2 + (size_t)c * 2048 * 8192, wT, 8192, 2048);
        gemm_bf16<2, false, false><<<dim3(64, 2, 2), 256, 0, stream>>>(
            h1b + c * 2048, 8192, wT, 2048, nullptr, cacc, 8192, 2048, 1024);
    }
    post_bias<false><<<(256 * 8192 / 4) / 256, 256, 0, stream>>>(cacc, b_in2, actb, 8191);

    // Two mamba layers
    for (int m = 0; m < 2; ++m) {
        // zx = act @ in_proj  (fp32 out)          [2048 x 4480p, K=1024]
        transpose_bf16<<<dim3(DPROJP / 64, 1024 / 64), 256, 0, stream>>>(m_in_proj[m], wT, DPROJ, 1024);
        gemm_bf16<0, false, false><<<dim3(DPROJP / 128, 16, 1), 256, 0, stream>>>(
            actb, 1024, wT, 1024, nullptr, zx, DPROJP, 1024, 1024);

        conv_kernel<<<(BATCHN * CONVD + 255) / 256, 256, 0, stream>>>(zx, m_conv_w[m], m_conv_b[m], xbc);
        dt_kernel<<<(ROWS * NH) / 256, 256, 0, stream>>>(zx, m_dt_bias[m], m_A_log[m], dtb, dab);
        scan_kernel<<<BATCHN * NH, 256, 0, stream>>>(xbc, dtb, dab, m_D[m], yf);
        gate_rms<<<ROWS, 256, 0, stream>>>(yf, zx, m_norm_w[m], yb);

        // act = y @ out_proj -> bf16              [2048 x 1024, K=2048]
        transpose_bf16<<<dim3(1024 / 64, 2048 / 64), 256, 0, stream>>>(m_out_proj[m], wT, 1024, 2048);
        gemm_bf16<1, false, false><<<dim3(8, 16, 1), 256, 0, stream>>>(
            yb, 2048, wT, 2048, nullptr, actb, 1024, 2048, 2048);
    }

    // f1 = relu(act @ w_out1 + b_out1) -> bf16    [256 x 1024, K=8192], split-K 16
    transpose_bf16<<<dim3(1024 / 64, 8192 / 64), 256, 0, stream>>>(w_out1, wT, 1024, 8192);
    hipMemsetAsync(cacc, 0, (size_t)256 * 1024 * 4, stream);
    gemm_bf16<2, false, false><<<dim3(8, 2, 16), 256, 0, stream>>>(
        actb, 8192, wT, 8192, nullptr, cacc, 1024, 8192, 512);
    post_bias<true><<<(256 * 1024 / 4) / 256, 256, 0, stream>>>(cacc, b_out1, f1b, 1023);

    // out = f1 @ w_out2 + b_out2                  [256 x 2, K=1024]
    final_out<<<64, 256, 0, stream>>>(f1b, w_out2, b_out2, out);
}

// Round 3
// 1019.750 us; speedup vs baseline: 4.4004x; 1.0045x over previous
//
#include <hip/hip_runtime.h>

// Problem constants
#define BATCHN 256
#define SEQL   8
#define HIDN   1024
#define DIN    2048
#define NH     32
#define HDIM   64
#define DST    128
#define CONVD  2304      // DIN + 2*DST
#define DPROJ  4384      // 2*DIN + 2*DST + NH
#define DPROJP 4480      // DPROJ padded to x128 for GEMM-N
#define ROWS   2048      // BATCH*SEQ

typedef float f32x4 __attribute__((ext_vector_type(4)));
typedef short bf16x8 __attribute__((ext_vector_type(8)));   // 8 bf16 in 4 VGPRs

__device__ __forceinline__ ushort f2bf(float f) {           // RNE fp32->bf16
    unsigned x = __float_as_uint(f);
    unsigned r = (x + 0x7fffu + ((x >> 16) & 1u)) >> 16;
    return (ushort)r;
}
__device__ __forceinline__ float bf2f(ushort u) {
    return __uint_as_float(((unsigned)u) << 16);
}
__device__ __forceinline__ unsigned packbf(float lo, float hi) {
    return (unsigned)f2bf(lo) | ((unsigned)f2bf(hi) << 16);
}

#define GL2LDS(g, l)                                                        \
    __builtin_amdgcn_global_load_lds(                                       \
        (const __attribute__((address_space(1))) void*)(g),                 \
        (__attribute__((address_space(3))) void*)(l), 16, 0, 0)

// ---------------------------------------------------------------------------
// Fused bf16 MFMA GEMM reading W in natural [K][N] fp32 layout.
//   C[M,N] = A[M,K](bf16) @ W[K,N](fp32, converted to bf16 in staging)
// 128x128 tile, BK=32, 256 threads = 4 waves (2x2), wave 64x64 via 4x4
// mfma_16x16x32_bf16. A staged with global_load_lds (linear LDS). B staged
// via reg: float4 load -> cvt -> ds_write_b32 of (k,k+1) bf16 pairs into
// n-major Bs[n][k] with XOR swizzle kk = k ^ (((n>>2)&3)<<3) (write 8-way,
// read <=2-way conflicts; hidden at 2-phase per regime gate).
// OM: 0 = fp32 store, 1 = bf16 store, 2 = fp32 atomicAdd (split-K).
// NG: guard W columns >= Nw (returns 0) for N not multiple of 128.
// Split-K via blockIdx.z * kchunk (kchunk multiple of 32, exact tiling).
// ---------------------------------------------------------------------------
template<int OM, bool BIASF, bool RELUF, bool NG>
__global__ __launch_bounds__(256)
void gemm_fw(const ushort* __restrict__ A, int lda,
             const float* __restrict__ W, int ldw, int Nw,
             const float* __restrict__ bias,
             void* __restrict__ Cv, int ldc, int kchunk)
{
    __shared__ __align__(16) ushort As[128 * 32];
    __shared__ __align__(16) ushort Bs[128 * 32];
    const int t    = threadIdx.x;
    const int row0 = blockIdx.y * 128;
    const int col0 = blockIdx.x * 128;
    const int kOff = blockIdx.z * kchunk;
    const int kEnd = kOff + kchunk;
    const int lane = t & 63;
    const int wv   = t >> 6;
    const int wr   = wv >> 1, wc = wv & 1;
    const int frow = lane & 15;
    const int fko  = (lane >> 4) * 8;

    f32x4 acc[4][4];
#pragma unroll
    for (int m = 0; m < 4; ++m)
#pragma unroll
        for (int n = 0; n < 4; ++n) acc[m][n] = f32x4{0.f, 0.f, 0.f, 0.f};

    // A staging map: 2 x global_load_lds(16B) covers 128x32 bf16.
    const int sRow = t >> 2;
    const int sCol = (t & 3) * 8;
    const ushort* aBase = A + (size_t)(row0 + sRow) * lda + sCol;
    ushort* aL = As + t * 8;

    // B staging map: thread handles k-pair (2*((t>>5)+8i)) x 4 cols (4*(t&31)).
    const int bn   = 4 * (t & 31);
    const int swz  = (t & 3) << 3;            // = ((bn>>2)&3)<<3

    for (int kg = kOff; kg < kEnd; kg += 32) {
        GL2LDS(aBase + kg, aL);
        GL2LDS(aBase + (size_t)64 * lda + kg, aL + 2048);
#pragma unroll
        for (int i = 0; i < 2; ++i) {
            const int k = 2 * ((t >> 5) + i * 8);
            const float* wp = W + (size_t)(kg + k) * ldw + col0 + bn;
            float w0[4], w1[4];
            if (!NG || (col0 + bn + 3 < Nw)) {
                float4 a4 = *reinterpret_cast<const float4*>(wp);
                float4 b4 = *reinterpret_cast<const float4*>(wp + ldw);
                w0[0] = a4.x; w0[1] = a4.y; w0[2] = a4.z; w0[3] = a4.w;
                w1[0] = b4.x; w1[1] = b4.y; w1[2] = b4.z; w1[3] = b4.w;
            } else {
#pragma unroll
                for (int e = 0; e < 4; ++e) {
                    const bool ok = (col0 + bn + e) < Nw;
                    w0[e] = ok ? wp[e] : 0.f;
                    w1[e] = ok ? wp[ldw + e] : 0.f;
                }
            }
            const int kk = k ^ swz;
#pragma unroll
            for (int j = 0; j < 4; ++j)
                *reinterpret_cast<unsigned*>(&Bs[(bn + j) * 32 + kk]) = packbf(w0[j], w1[j]);
        }
        __syncthreads();
        bf16x8 af[4], bfr[4];
#pragma unroll
        for (int m = 0; m < 4; ++m)
            af[m] = *reinterpret_cast<const bf16x8*>(&As[(wr * 64 + m * 16 + frow) * 32 + fko]);
#pragma unroll
        for (int n = 0; n < 4; ++n) {
            const int row = wc * 64 + n * 16 + frow;
            const int kkr = fko ^ (((row >> 2) & 3) << 3);
            bfr[n] = *reinterpret_cast<const bf16x8*>(&Bs[row * 32 + kkr]);
        }
#pragma unroll
        for (int m = 0; m < 4; ++m)
#pragma unroll
            for (int n = 0; n < 4; ++n)
                acc[m][n] = __builtin_amdgcn_mfma_f32_16x16x32_bf16(af[m], bfr[n], acc[m][n], 0, 0, 0);
        __syncthreads();
    }

    float*  Cf = (float*)Cv;
    ushort* Cb = (ushort*)Cv;
    const int colBase = col0 + wc * 64;
    const int rowBase = row0 + wr * 64 + (lane >> 4) * 4;
#pragma unroll
    for (int n = 0; n < 4; ++n) {
        const int col = colBase + n * 16 + frow;
        const float bv = BIASF ? bias[col] : 0.f;
#pragma unroll
        for (int m = 0; m < 4; ++m) {
#pragma unroll
            for (int r = 0; r < 4; ++r) {
                const int row = rowBase + m * 16 + r;
                float v = acc[m][n][r] + bv;
                if (RELUF) v = fmaxf(v, 0.f);
                if (OM == 0)      Cf[(size_t)row * ldc + col] = v;
                else if (OM == 1) Cb[(size_t)row * ldc + col] = f2bf(v);
                else              atomicAdd(&Cf[(size_t)row * ldc + col], v);
            }
        }
    }
}

// ---------------------------------------------------------------------------
// fp32 -> bf16 elementwise (x input). 4 elems/thread.
// ---------------------------------------------------------------------------
__global__ __launch_bounds__(256)
void convert_bf16(const float* __restrict__ in, ushort* __restrict__ out)
{
    int i = (blockIdx.x * 256 + threadIdx.x) * 4;
    float4 v = *reinterpret_cast<const float4*>(&in[i]);
    ushort4 o = {f2bf(v.x), f2bf(v.y), f2bf(v.z), f2bf(v.w)};
    *reinterpret_cast<ushort4*>(&out[i]) = o;
}

// ---------------------------------------------------------------------------
// Split-K epilogue: out_bf16 = [relu](acc + bias[col]).  N power of 2.
// ---------------------------------------------------------------------------
template<bool RELUF>
__global__ __launch_bounds__(256)
void post_bias(const float* __restrict__ acc, const float* __restrict__ bias,
               ushort* __restrict__ out, int nmask)
{
    int i = (blockIdx.x * 256 + threadIdx.x) * 4;
    float4 v = *reinterpret_cast<const float4*>(&acc[i]);
    int col = i & nmask;
    float4 b = *reinterpret_cast<const float4*>(&bias[col]);
    float r0 = v.x + b.x, r1 = v.y + b.y, r2 = v.z + b.z, r3 = v.w + b.w;
    if (RELUF) {
        r0 = fmaxf(r0, 0.f); r1 = fmaxf(r1, 0.f);
        r2 = fmaxf(r2, 0.f); r3 = fmaxf(r3, 0.f);
    }
    ushort4 o = {f2bf(r0), f2bf(r1), f2bf(r2), f2bf(r3)};
    *reinterpret_cast<ushort4*>(&out[i]) = o;
}

// ---------------------------------------------------------------------------
// Depthwise causal conv over L=8 (+bias, silu). One thread per (b, channel).
// zx stride DPROJP. Output xbc (ROWS x CONVD), activated.
// ---------------------------------------------------------------------------
__global__ __launch_bounds__(256)
void conv_kernel(const float* __restrict__ zx, const float* __restrict__ cw,
                 const float* __restrict__ cb, float* __restrict__ xbc)
{
    int g = blockIdx.x * 256 + threadIdx.x;
    if (g >= BATCHN * CONVD) return;
    int c = g % CONVD;
    int b = g / CONVD;
    float x8[SEQL];
#pragma unroll
    for (int l = 0; l < SEQL; ++l)
        x8[l] = zx[(size_t)(b * SEQL + l) * DPROJP + DIN + c];
    float w0 = cw[c * 4 + 0], w1 = cw[c * 4 + 1];
    float w2 = cw[c * 4 + 2], w3 = cw[c * 4 + 3];
    float bb = cb[c];
#pragma unroll
    for (int l = 0; l < SEQL; ++l) {
        float s = bb;
        if (l >= 3) s = fmaf(w0, x8[l - 3], s);
        if (l >= 2) s = fmaf(w1, x8[l - 2], s);
        if (l >= 1) s = fmaf(w2, x8[l - 1], s);
        s = fmaf(w3, x8[l], s);
        float a = s / (1.f + __expf(-s));
        xbc[(size_t)(b * SEQL + l) * CONVD + c] = a;
    }
}

__global__ __launch_bounds__(256)
void dt_kernel(const float* __restrict__ zx, const float* __restrict__ dt_bias,
               const float* __restrict__ A_log, float* __restrict__ dtb,
               float* __restrict__ dab)
{
    int i = blockIdx.x * 256 + threadIdx.x;      // row*NH + h
    if (i >= ROWS * NH) return;
    int row = i >> 5, h = i & 31;
    float v = zx[(size_t)row * DPROJP + (DIN + CONVD) + h] + dt_bias[h];
    float dt = (v > 20.f) ? v : log1pf(__expf(v));
    float dA = __expf(-__expf(A_log[h]) * dt);
    dtb[i] = dt;
    dab[i] = dA;
}

// ---------------------------------------------------------------------------
// Selective scan. One block per (b, h). 256 threads: t = sc*64 + p.
// ---------------------------------------------------------------------------
__global__ __launch_bounds__(256)
void scan_kernel(const float* __restrict__ xbc, const float* __restrict__ dtb,
                 const float* __restrict__ dab, const float* __restrict__ Dv,
                 float* __restrict__ y)
{
    const int b  = blockIdx.x >> 5;
    const int h  = blockIdx.x & 31;
    const int t  = threadIdx.x;
    const int sc = t >> 6;
    const int p  = t & 63;
    __shared__ float BC[256];
    __shared__ float part[256];
    float st[32];
#pragma unroll
    for (int j = 0; j < 32; ++j) st[j] = 0.f;
    const float Dh = Dv[h];

    for (int l = 0; l < SEQL; ++l) {
        const int row = b * SEQL + l;
        BC[t] = xbc[(size_t)row * CONVD + DIN + t];
        __syncthreads();
        const float dA = dab[row * NH + h];
        const float dt = dtb[row * NH + h];
        const float xp = xbc[(size_t)row * CONVD + h * HDIM + p];
        const float coef = dt * xp;
        float acc = 0.f;
#pragma unroll
        for (int j = 0; j < 32; ++j) {
            const int s = sc * 32 + j;
            st[j] = fmaf(dA, st[j], coef * BC[s]);
            acc = fmaf(st[j], BC[128 + s], acc);
        }
        part[t] = acc;
        __syncthreads();
        if (sc == 0) {
            float yv = part[p] + part[64 + p] + part[128 + p] + part[192 + p];
            y[(size_t)row * DIN + h * HDIM + p] = yv + Dh * xp;
        }
    }
}

// ---------------------------------------------------------------------------
// y = y * silu(z); rmsnorm over 2048; * norm_w; emit bf16.
// ---------------------------------------------------------------------------
__global__ __launch_bounds__(256)
void gate_rms(const float* __restrict__ y, const float* __restrict__ zx,
              const float* __restrict__ nw, ushort* __restrict__ yb)
{
    const int row = blockIdx.x;
    const int t = threadIdx.x;
    float g[8];
    float ss = 0.f;
#pragma unroll
    for (int i = 0; i < 8; ++i) {
        int d = t + i * 256;
        float yv = y[(size_t)row * DIN + d];
        float zv = zx[(size_t)row * DPROJP + d];
        float sil = zv / (1.f + __expf(-zv));
        float gv = yv * sil;
        g[i] = gv;
        ss = fmaf(gv, gv, ss);
    }
#pragma unroll
    for (int o = 32; o >= 1; o >>= 1) ss += __shfl_xor(ss, o, 64);
    __shared__ float red[4];
    if ((t & 63) == 0) red[t >> 6] = ss;
    __syncthreads();
    float tot = red[0] + red[1] + red[2] + red[3];
    float scale = rsqrtf(tot * (1.f / DIN) + 1e-5f);
#pragma unroll
    for (int i = 0; i < 8; ++i) {
        int d = t + i * 256;
        yb[(size_t)row * DIN + d] = f2bf(g[i] * scale * nw[d]);
    }
}

// ---------------------------------------------------------------------------
// Final tiny GEMM: out[256,2] = f1b(bf16) @ w_out2(fp32) + b_out2.
// ---------------------------------------------------------------------------
__global__ __launch_bounds__(256)
void final_out(const ushort* __restrict__ f1b, const float* __restrict__ w2,
               const float* __restrict__ b2, float* __restrict__ out)
{
    int row  = blockIdx.x * 4 + (threadIdx.x >> 6);
    int lane = threadIdx.x & 63;
    float a0 = 0.f, a1 = 0.f;
#pragma unroll
    for (int i = 0; i < 16; ++i) {
        int k = lane + i * 64;
        float f = bf2f(f1b[row * 1024 + k]);
        a0 = fmaf(f, w2[k * 2 + 0], a0);
        a1 = fmaf(f, w2[k * 2 + 1], a1);
    }
#pragma unroll
    for (int o = 32; o >= 1; o >>= 1) {
        a0 += __shfl_xor(a0, o, 64);
        a1 += __shfl_xor(a1, o, 64);
    }
    if (lane == 0) {
        out[row * 2 + 0] = a0 + b2[0];
        out[row * 2 + 1] = a1 + b2[1];
    }
}

// ---------------------------------------------------------------------------
extern "C" void kernel_launch(void* const* d_in, const int* in_sizes, int n_in,
                              void* d_out, int out_size, void* d_ws, size_t ws_size,
                              hipStream_t stream)
{
    const float* x      = (const float*)d_in[0];
    const float* w_in1  = (const float*)d_in[1];
    const float* b_in1  = (const float*)d_in[2];
    const float* w_in2  = (const float*)d_in[3];
    const float* b_in2  = (const float*)d_in[4];
    const float* m_in_proj[2]  = {(const float*)d_in[5],  (const float*)d_in[13]};
    const float* m_conv_w[2]   = {(const float*)d_in[6],  (const float*)d_in[14]};
    const float* m_conv_b[2]   = {(const float*)d_in[7],  (const float*)d_in[15]};
    const float* m_dt_bias[2]  = {(const float*)d_in[8],  (const float*)d_in[16]};
    const float* m_A_log[2]    = {(const float*)d_in[9],  (const float*)d_in[17]};
    const float* m_D[2]        = {(const float*)d_in[10], (const float*)d_in[18]};
    const float* m_norm_w[2]   = {(const float*)d_in[11], (const float*)d_in[19]};
    const float* m_out_proj[2] = {(const float*)d_in[12], (const float*)d_in[20]};
    const float* w_out1 = (const float*)d_in[21];
    const float* b_out1 = (const float*)d_in[22];
    const float* w_out2 = (const float*)d_in[23];
    const float* b_out2 = (const float*)d_in[24];
    float* out = (float*)d_out;

    // Workspace layout (bytes). Total ~94 MiB.
    char* p = (char*)d_ws;
    ushort* xb   = (ushort*)p;                 p += (size_t)256 * 1024 * 2;
    ushort* h1b  = (ushort*)p;                 p += (size_t)256 * 8192 * 2;
    ushort* actb = (ushort*)p;                 p += (size_t)2048 * 1024 * 2;
    float*  cacc = (float*)p;                  p += (size_t)256 * 8192 * 4;   // split-K accum
    float*  zx   = (float*)p;                  p += (size_t)ROWS * DPROJP * 4;
    float*  xbc  = (float*)p;                  p += (size_t)ROWS * CONVD * 4;
    float*  dtb  = (float*)p;                  p += (size_t)ROWS * NH * 4;
    float*  dab  = (float*)p;                  p += (size_t)ROWS * NH * 4;
    float*  yf   = (float*)p;                  p += (size_t)ROWS * DIN * 4;
    ushort* yb   = (ushort*)p;                 p += (size_t)ROWS * DIN * 2;
    ushort* f1b  = (ushort*)p;                 p += (size_t)256 * 1024 * 2;

    // x -> bf16
    convert_bf16<<<256, 256, 0, stream>>>(x, xb);

    // h1 = relu(x @ w_in1 + b1) -> bf16          [256 x 8192, K=1024]
    gemm_fw<1, true, true, false><<<dim3(64, 2, 1), 256, 0, stream>>>(
        xb, 1024, w_in1, 8192, 8192, b_in1, h1b, 8192, 1024);

    // act = h1 @ w_in2 + b2 -> bf16              [256 x 8192, K=8192], split-K 4
    hipMemsetAsync(cacc, 0, (size_t)256 * 8192 * 4, stream);
    gemm_fw<2, false, false, false><<<dim3(64, 2, 4), 256, 0, stream>>>(
        h1b, 8192, w_in2, 8192, 8192, nullptr, cacc, 8192, 2048);
    post_bias<false><<<(256 * 8192 / 4) / 256, 256, 0, stream>>>(cacc, b_in2, actb, 8191);

    // Two mamba layers
    for (int m = 0; m < 2; ++m) {
        // zx = act @ in_proj  (fp32 out)          [2048 x 4480p, K=1024], N-guard 4384
        gemm_fw<0, false, false, true><<<dim3(DPROJP / 128, 16, 1), 256, 0, stream>>>(
            actb, 1024, m_in_proj[m], DPROJ, DPROJ, nullptr, zx, DPROJP, 1024);

        conv_kernel<<<(BATCHN * CONVD + 255) / 256, 256, 0, stream>>>(zx, m_conv_w[m], m_conv_b[m], xbc);
        dt_kernel<<<(ROWS * NH) / 256, 256, 0, stream>>>(zx, m_dt_bias[m], m_A_log[m], dtb, dab);
        scan_kernel<<<BATCHN * NH, 256, 0, stream>>>(xbc, dtb, dab, m_D[m], yf);
        gate_rms<<<ROWS, 256, 0, stream>>>(yf, zx, m_norm_w[m], yb);

        // act = y @ out_proj -> bf16              [2048 x 1024, K=2048]
        gemm_fw<1, false, false, false><<<dim3(8, 16, 1), 256, 0, stream>>>(
            yb, 2048, m_out_proj[m], 1024, 1024, nullptr, actb, 1024, 2048);
    }

    // f1 = relu(act @ w_out1 + b_out1) -> bf16    [256 x 1024, K=8192], split-K 8
    hipMemsetAsync(cacc, 0, (size_t)256 * 1024 * 4, stream);
    gemm_fw<2, false, false, false><<<dim3(8, 2, 8), 256, 0, stream>>>(
        actb, 8192, w_out1, 1024, 1024, nullptr, cacc, 1024, 1024);
    post_bias<true><<<(256 * 1024 / 4) / 256, 256, 0, stream>>>(cacc, b_out1, f1b, 1023);

    // out = f1 @ w_out2 + b_out2                  [256 x 2, K=1024]
    final_out<<<64, 256, 0, stream>>>(f1b, w_out2, b_out2, out);
}